// Round 13
// baseline (466.849 us; speedup 1.0000x reference)
//
#include <hip/hip_runtime.h>
#include <hip/hip_bf16.h>
#include <hip/hip_fp8.h>
#include <math.h>

#define N 4096
#define D 1024
#define NINST 8
#define NGROUP (N / NINST)
#define ALPHA 20.0f
#define MARGIN 0.5f
#define NB 64                        // 64-row bands
#define NTILE (NB * (NB + 1) / 2)    // 2080 triangular tiles
#define NBLK 260                     // 260 blocks x 8 waves = 2080 tile-waves

typedef __attribute__((ext_vector_type(4))) float f32x4;

__device__ __forceinline__ unsigned fkey(float f) {
    int b = __float_as_int(f);
    return (b >= 0) ? ((unsigned)b | 0x80000000u) : ~(unsigned)b;
}
__device__ __forceinline__ float fdec(unsigned u) {
    int b = (u & 0x80000000u) ? (int)(u ^ 0x80000000u) : ~(int)u;
    return __int_as_float(b);
}

__device__ __forceinline__ float softplus(float x) {
    float z = __expf(-fabsf(x));
    return fmaxf(x, 0.0f) + __logf(1.0f + z);
}

__device__ __forceinline__ void gld16(const void* g, void* l) {
    __builtin_amdgcn_global_load_lds(
        (const __attribute__((address_space(1))) void*)g,
        (__attribute__((address_space(3))) void*)l, 16, 0, 0);
}

// agent-scope grid sync: release-add by t0, acquire-spin by one lane per wave.
__device__ __forceinline__ void grid_sync(unsigned* sem, unsigned target, int t) {
    __syncthreads();
    if (t == 0)
        __hip_atomic_fetch_add(sem, 1u, __ATOMIC_RELEASE, __HIP_MEMORY_SCOPE_AGENT);
    if ((t & 63) == 0) {
        while (__hip_atomic_load(sem, __ATOMIC_ACQUIRE, __HIP_MEMORY_SCOPE_AGENT) < target)
            __builtin_amdgcn_s_sleep(2);
    }
    __syncthreads();
}

// ---------------- fused persistent kernel ----------------
// grid 260 x 512 threads. LDS union: phase1 two-group staging (66.7KB) /
// phase2 per-wave depth-2 DMA rings (64KB) / phase3 sloss (64B).
__global__ __launch_bounds__(512, 4) void k_fused(const float* __restrict__ in,
                                                  unsigned long* __restrict__ xn8,
                                                  float* __restrict__ pos_sims,
                                                  float* __restrict__ min_pos,
                                                  float* __restrict__ sum_part,
                                                  int* __restrict__ cnt_part,
                                                  float* __restrict__ max_part,
                                                  unsigned* __restrict__ sems,  // [gmax,s1,s2,cnt]
                                                  float* __restrict__ accum,    // 32 floats
                                                  float* __restrict__ out) {
    __shared__ __align__(16) char smem[66816];
    unsigned* gmax = sems + 0;
    unsigned* s1   = sems + 1;
    unsigned* s2   = sems + 2;
    unsigned* cnt  = sems + 3;

    int bid = blockIdx.x;
    int t = threadIdx.x;

    // ===================== PHASE 1: normalize + fp8 + Gram =====================
    if (bid < 256) {
        int h = t >> 8;            // wave-half 0/1 -> group parity
        int tt = t & 255;
        int group = bid * 2 + h;   // 0..511
        int lane = tt & 63, wid4 = tt >> 6;

        float4* srows4 = (float4*)(smem + h * 32912);            // [8*257]
        float (*spart)[4] = (float(*)[4])(smem + 65824 + h * 128);
        float* sinv = (float*)(smem + 66080 + h * 32);
        float (*sg)[8] = (float(*)[8])(smem + 66144 + h * 256);

        const float4* in4 = (const float4*)in;
        #pragma unroll
        for (int i = 0; i < 8; ++i) {
            float4 v = in4[(size_t)group * 2048 + i * 256 + tt];
            srows4[i * 257 + tt] = v;
            float ss = v.x * v.x + v.y * v.y + v.z * v.z + v.w * v.w;
            #pragma unroll
            for (int off = 1; off < 64; off <<= 1) ss += __shfl_xor(ss, off);
            if (lane == 0) spart[i][wid4] = ss;
        }
        __syncthreads();
        if (tt < 8) sinv[tt] = rsqrtf(spart[tt][0] + spart[tt][1] + spart[tt][2] + spart[tt][3]);
        __syncthreads();

        // fragment-major fp8 write (layout as R10-R12)
        {
            int i_row = tt & 7;
            int oct  = (tt >> 3) & 3;
            int k0b  = tt >> 5;
            size_t base = (size_t)(group >> 3) * 8192 + (size_t)((group >> 1) & 3) * 64
                        + (size_t)(oct * 16 + (group & 1) * 8 + i_row);
            float inv = sinv[i_row];
            #pragma unroll
            for (int j = 0; j < 4; ++j) {
                int k0 = k0b + j * 8;
                float4 v0 = srows4[i_row * 257 + k0 * 8 + oct * 2];
                float4 v1 = srows4[i_row * 257 + k0 * 8 + oct * 2 + 1];
                union { unsigned char c[8]; unsigned long u64; } o;
                o.c[0] = __hip_fp8_e4m3(v0.x * inv).__x;
                o.c[1] = __hip_fp8_e4m3(v0.y * inv).__x;
                o.c[2] = __hip_fp8_e4m3(v0.z * inv).__x;
                o.c[3] = __hip_fp8_e4m3(v0.w * inv).__x;
                o.c[4] = __hip_fp8_e4m3(v1.x * inv).__x;
                o.c[5] = __hip_fp8_e4m3(v1.y * inv).__x;
                o.c[6] = __hip_fp8_e4m3(v1.z * inv).__x;
                o.c[7] = __hip_fp8_e4m3(v1.w * inv).__x;
                xn8[base + (size_t)k0 * 256] = o.u64;
            }
        }

        int pair = tt >> 2, a = pair >> 3, b = pair & 7, slice = tt & 3;
        const float4* pa = srows4 + a * 257 + slice * 64;
        const float4* pb = srows4 + b * 257 + slice * 64;
        float s = 0.f;
        #pragma unroll 8
        for (int i = 0; i < 64; ++i) {
            float4 x = pa[i], y = pb[i];
            s += x.x * y.x + x.y * y.y + x.z * y.z + x.w * y.w;
        }
        s += __shfl_xor(s, 1);
        s += __shfl_xor(s, 2);
        if (slice == 0) sg[a][b] = s * sinv[a] * sinv[b];
        __syncthreads();
        if (tt < 8) {
            float mn = 1e30f;
            int idx = 0;
            #pragma unroll
            for (int b2 = 0; b2 < 8; ++b2) {
                if (b2 == tt) continue;
                float v = sg[tt][b2];
                mn = fminf(mn, v);
                pos_sims[(size_t)(group * 8 + tt) * 8 + idx] = v;
                ++idx;
            }
            min_pos[group * 8 + tt] = mn;
        }
    }

    grid_sync(s1, NBLK, t);

    // ===================== PHASE 2: fp8 MFMA sim tiles =====================
    {
        int w = t >> 6;             // wave 0..7
        int l = t & 63;
        int u = bid * 8 + w;        // tile 0..2079, exactly one per wave

        int rt = 0, rem = u;
        while (rem >= NB - rt) { rem -= NB - rt; ++rt; }
        int ct = rt + rem;
        bool diag = (rt == ct);

        int R0 = rt * 64, C0 = ct * 64;
        int lrow = l & 15;
        int kgrp = l >> 4;

        float mA = min_pos[R0 + l];
        float mB = min_pos[C0 + l];
        asm volatile("s_waitcnt vmcnt(0)" ::: "memory");   // exact vmcnt bookkeeping

        const char* xb = (const char*)xn8;
        const char* gA = xb + (size_t)rt * 65536 + (size_t)l * 16;
        const char* gB = xb + (size_t)ct * 65536 + (size_t)l * 16;
        char* ring = smem + w * 8192;   // 2 stages x 4KB

        #define STAGE(s_)                                                \
            do {                                                         \
                char* d_ = ring + ((s_) & 1) * 4096;                     \
                gld16(gA + (size_t)(s_) * 2048,        d_);              \
                gld16(gA + (size_t)(s_) * 2048 + 1024, d_ + 1024);       \
                gld16(gB + (size_t)(s_) * 2048,        d_ + 2048);       \
                gld16(gB + (size_t)(s_) * 2048 + 1024, d_ + 3072);       \
            } while (0)

        STAGE(0); STAGE(1);

        f32x4 zero = {0.f, 0.f, 0.f, 0.f};
        f32x4 acc[4][4];
        #pragma unroll
        for (int m = 0; m < 4; ++m)
            #pragma unroll
            for (int n = 0; n < 4; ++n) acc[m][n] = zero;

        for (int it = 0; it < 32; ++it) {
            if (it <= 30) asm volatile("s_waitcnt vmcnt(4)" ::: "memory");
            else          asm volatile("s_waitcnt vmcnt(0)" ::: "memory");

            const char* buf = ring + (it & 1) * 4096;
            long a[4], b[4];
            #pragma unroll
            for (int m = 0; m < 4; ++m) {
                a[m] = *(const long*)(buf + m * 512 + l * 8);
                b[m] = *(const long*)(buf + 2048 + m * 512 + l * 8);
            }

            #pragma unroll
            for (int m = 0; m < 4; ++m)
                #pragma unroll
                for (int n = 0; n < 4; ++n)
                    acc[m][n] = __builtin_amdgcn_mfma_f32_16x16x32_fp8_fp8(
                        a[m], b[n], acc[m][n], 0, 0, 0);

            asm volatile("s_waitcnt lgkmcnt(0)" ::: "memory");
            if (it <= 29) STAGE(it + 2);
        }
        #undef STAGE

        // epilogue: row-band stats; col-band (transpose) stats for off-diag
        float allmax = -1e30f;
        float thB[4];
        #pragma unroll
        for (int n = 0; n < 4; ++n) thB[n] = __shfl(mB, n * 16 + lrow) - 0.05f;

        float colS[4] = {0.f, 0.f, 0.f, 0.f};
        float colM[4] = {-1e30f, -1e30f, -1e30f, -1e30f};
        int   colC[4] = {0, 0, 0, 0};

        #pragma unroll
        for (int m = 0; m < 4; ++m) {
            #pragma unroll
            for (int reg = 0; reg < 4; ++reg) {
                int lr = m * 16 + kgrp * 4 + reg;
                int grow = R0 + lr;
                float th = __shfl(mA, lr) - 0.05f;
                int gi = grow >> 3;
                float rs = 0.f, rm = -1e30f;
                int rc = 0;
                #pragma unroll
                for (int n = 0; n < 4; ++n) {
                    int gcol = C0 + n * 16 + lrow;
                    float s = acc[m][n][reg];
                    allmax = fmaxf(allmax, s);
                    if ((gcol >> 3) != gi) {
                        float e = softplus(ALPHA * (s - MARGIN));
                        rm = fmaxf(rm, s);
                        if (s > th) { rs += e; rc += 1; }
                        if (!diag) {
                            colM[n] = fmaxf(colM[n], s);
                            if (s > thB[n]) { colS[n] += e; colC[n] += 1; }
                        }
                    }
                }
                #pragma unroll
                for (int off = 1; off < 16; off <<= 1) {
                    rs += __shfl_xor(rs, off);
                    rc += __shfl_xor(rc, off);
                    rm = fmaxf(rm, __shfl_xor(rm, off));
                }
                if (lrow == 0) {
                    sum_part[(size_t)grow * 64 + ct] = rs;
                    cnt_part[(size_t)grow * 64 + ct] = rc;
                    max_part[(size_t)grow * 64 + ct] = rm;
                }
            }
        }

        if (!diag) {
            #pragma unroll
            for (int n = 0; n < 4; ++n) {
                float cs = colS[n], cm = colM[n];
                int cc = colC[n];
                cs += __shfl_xor(cs, 16); cs += __shfl_xor(cs, 32);
                cc += __shfl_xor(cc, 16); cc += __shfl_xor(cc, 32);
                cm = fmaxf(cm, __shfl_xor(cm, 16));
                cm = fmaxf(cm, __shfl_xor(cm, 32));
                if (kgrp == 0) {
                    int gcol = C0 + n * 16 + lrow;
                    sum_part[(size_t)gcol * 64 + rt] = cs;
                    cnt_part[(size_t)gcol * 64 + rt] = cc;
                    max_part[(size_t)gcol * 64 + rt] = cm;
                }
            }
        }

        #pragma unroll
        for (int off = 1; off < 64; off <<= 1) allmax = fmaxf(allmax, __shfl_xor(allmax, off));
        if (l == 0) atomicMax(gmax, fkey(allmax));
    }

    grid_sync(s2, NBLK, t);

    // ===================== PHASE 3: per-row combine + mean =====================
    if (bid < 256) {
        float* sloss = (float*)smem;   // 16 floats
        float blocksum = 0.f;
        #pragma unroll
        for (int iter = 0; iter < 2; ++iter) {
            int row = bid * 16 + iter * 8 + (t >> 6);
            int lane = t & 63;
            float ns = sum_part[(size_t)row * 64 + lane];
            int nc = cnt_part[(size_t)row * 64 + lane];
            float nm = max_part[(size_t)row * 64 + lane];
            #pragma unroll
            for (int off = 1; off < 64; off <<= 1) {
                ns += __shfl_xor(ns, off);
                nc += __shfl_xor(nc, off);
                nm = fmaxf(nm, __shfl_xor(nm, off));
            }
            if (lane == 0) {
                float base = fmaxf(fdec(*gmax) - 0.1f, MARGIN + 0.2f);
                float neg_loss = (nc > 0) ? ns / (float)nc : softplus(ALPHA * (nm - MARGIN));
                float ps = 0.f;
                int pcnt = 0;
                float mn = min_pos[row];
                #pragma unroll
                for (int i = 0; i < NINST - 1; ++i) {
                    float s = pos_sims[(size_t)row * 8 + i];
                    if (s < base) { ps += softplus(-2.0f * (s - MARGIN)); pcnt++; }
                }
                float pos_loss = (pcnt > 0) ? ps / (float)pcnt : softplus(-2.0f * (mn - MARGIN));
                sloss[iter * 8 + (t >> 6)] = pos_loss + neg_loss;
            }
        }
        __syncthreads();
        if (t == 0) {
            #pragma unroll
            for (int i = 0; i < 16; ++i) blocksum += sloss[i];
            atomicAdd(&accum[bid & 31], blocksum);
            __threadfence();
            unsigned old = atomicAdd(cnt, 1u);
            if (old == 255u) {
                __threadfence();
                float tot = 0.f;
                for (int j = 0; j < 32; ++j) tot += atomicAdd(&accum[j], 0.0f);
                out[0] = tot / (float)N;
            }
        }
    }
}

extern "C" void kernel_launch(void* const* d_in, const int* in_sizes, int n_in,
                              void* d_out, int out_size, void* d_ws, size_t ws_size,
                              hipStream_t stream) {
    const float* in = (const float*)d_in[0];
    float* out = (float*)d_out;

    char* ws = (char*)d_ws;
    unsigned long* xn8 = (unsigned long*)(ws);                  // 4 MB (banded fragment-major)
    float*   min_pos  = (float*)(ws + 8388608 + 16384);         // 16 KB
    float*   pos_sims = (float*)(ws + 8388608 + 32768);         // 128 KB
    float*   sum_part = (float*)(ws + 8388608 + 32768 + 131072);            // 1 MB
    float*   max_part = (float*)(ws + 8388608 + 32768 + 131072 + 1048576);  // 1 MB
    int*     cnt_part = (int*)  (ws + 8388608 + 32768 + 131072 + 2097152);  // 1 MB
    unsigned* sems    = (unsigned*)(ws + 8388608 + 32768 + 131072 + 3145728);       // 4 u32
    float*   accum    = (float*)(ws + 8388608 + 32768 + 131072 + 3145728 + 128);    // 32 floats

    // zero gmax/s1/s2/cnt/accum each launch (capture-safe, deterministic)
    hipMemsetAsync(sems, 0, 256 + 128, stream);

    k_fused<<<NBLK, 512, 0, stream>>>(in, xn8, pos_sims, min_pos,
                                      sum_part, cnt_part, max_part,
                                      sems, accum, out);
}

// Round 14
// 117.703 us; speedup vs baseline: 3.9663x; 3.9663x over previous
//
#include <hip/hip_runtime.h>
#include <hip/hip_bf16.h>
#include <hip/hip_fp8.h>
#include <math.h>

#define N 4096
#define D 1024
#define NINST 8
#define NGROUP (N / NINST)
#define ALPHA 20.0f
#define MARGIN 0.5f
#define NB 64            // 64-row bands
#define NTILE (NB * (NB + 1) / 2)   // 2080 triangular tiles

typedef __attribute__((ext_vector_type(4))) float f32x4;

__device__ __forceinline__ unsigned fkey(float f) {
    int b = __float_as_int(f);
    return (b >= 0) ? ((unsigned)b | 0x80000000u) : ~(unsigned)b;
}
__device__ __forceinline__ float fdec(unsigned u) {
    int b = (u & 0x80000000u) ? (int)(u ^ 0x80000000u) : ~(int)u;
    return __int_as_float(b);
}

// stable fast softplus: log1p(exp(x)) = max(x,0) + log(1 + exp(-|x|))
__device__ __forceinline__ float softplus(float x) {
    float z = __expf(-fabsf(x));
    return fmaxf(x, 0.0f) + __logf(1.0f + z);
}

// async global -> LDS, 16 bytes per lane (lds dest: wave-uniform base + lane*16)
__device__ __forceinline__ void gld16(const void* g, void* l) {
    __builtin_amdgcn_global_load_lds(
        (const __attribute__((address_space(1))) void*)g,
        (__attribute__((address_space(3))) void*)l, 16, 0, 0);
}

// ---------------- K1: per-group normalize + banded fragment-major fp8 write + fp32 Gram ----
// xn8 layout (ulong units): idx = band*8192 + kstep*256 + m*64 + slot, where
// band = row>>6, m = (row>>4)&3, slot = oct*16 + (row&15); the ulong holds row's
// fp8 bytes [kstep*32 + oct*8, +8). One (band,kstep) panel = 2KB contiguous.
__global__ __launch_bounds__(256) void k_normpos(const float* __restrict__ in,
                                                 unsigned long* __restrict__ xn8,
                                                 float* __restrict__ pos_sims,
                                                 float* __restrict__ min_pos,
                                                 unsigned* __restrict__ gmax,
                                                 float* __restrict__ accum,
                                                 unsigned* __restrict__ cnt) {
    __shared__ float4 srows4[8 * 257];   // padded stride: no Gram bank conflicts
    __shared__ float spart[8][4];
    __shared__ float sinv[8];
    __shared__ float sg[8][8];

    int g = blockIdx.x;
    int t = threadIdx.x;
    int lane = t & 63, wid = t >> 6;

    if (g == 0) {
        if (t == 0) { *gmax = 0u; *cnt = 0u; }
        if (t < 32) accum[t] = 0.f;
    }

    const float4* in4 = (const float4*)in;
    #pragma unroll
    for (int i = 0; i < 8; ++i) {
        float4 v = in4[(size_t)g * 2048 + i * 256 + t];
        srows4[i * 257 + t] = v;
        float ss = v.x * v.x + v.y * v.y + v.z * v.z + v.w * v.w;
        #pragma unroll
        for (int off = 1; off < 64; off <<= 1) ss += __shfl_xor(ss, off);
        if (lane == 0) spart[i][wid] = ss;
    }
    __syncthreads();
    if (t < 8) sinv[t] = rsqrtf(spart[t][0] + spart[t][1] + spart[t][2] + spart[t][3]);
    __syncthreads();

    // fragment-major fp8 write: 4 ulong slots per thread
    {
        int i_row = t & 7;              // local row 0..7
        int oct  = (t >> 3) & 3;        // k-octet
        int k0b  = t >> 5;              // 0..7
        size_t base = (size_t)(g >> 3) * 8192 + (size_t)((g >> 1) & 3) * 64
                    + (size_t)(oct * 16 + (g & 1) * 8 + i_row);
        float inv = sinv[i_row];
        #pragma unroll
        for (int j = 0; j < 4; ++j) {
            int k0 = k0b + j * 8;       // 0..31
            float4 v0 = srows4[i_row * 257 + k0 * 8 + oct * 2];
            float4 v1 = srows4[i_row * 257 + k0 * 8 + oct * 2 + 1];
            union { unsigned char c[8]; unsigned long u64; } o;
            o.c[0] = __hip_fp8_e4m3(v0.x * inv).__x;
            o.c[1] = __hip_fp8_e4m3(v0.y * inv).__x;
            o.c[2] = __hip_fp8_e4m3(v0.z * inv).__x;
            o.c[3] = __hip_fp8_e4m3(v0.w * inv).__x;
            o.c[4] = __hip_fp8_e4m3(v1.x * inv).__x;
            o.c[5] = __hip_fp8_e4m3(v1.y * inv).__x;
            o.c[6] = __hip_fp8_e4m3(v1.z * inv).__x;
            o.c[7] = __hip_fp8_e4m3(v1.w * inv).__x;
            xn8[base + (size_t)k0 * 256] = o.u64;
        }
    }

    int pair = t >> 2, a = pair >> 3, b = pair & 7, slice = t & 3;
    const float4* pa = srows4 + a * 257 + slice * 64;
    const float4* pb = srows4 + b * 257 + slice * 64;
    float s = 0.f;
    #pragma unroll 8
    for (int i = 0; i < 64; ++i) {
        float4 x = pa[i], y = pb[i];
        s += x.x * y.x + x.y * y.y + x.z * y.z + x.w * y.w;
    }
    s += __shfl_xor(s, 1);
    s += __shfl_xor(s, 2);
    if (slice == 0) sg[a][b] = s * sinv[a] * sinv[b];
    __syncthreads();
    if (t < 8) {
        float mn = 1e30f;
        int idx = 0;
        #pragma unroll
        for (int b2 = 0; b2 < 8; ++b2) {
            if (b2 == t) continue;
            float v = sg[t][b2];
            mn = fminf(mn, v);
            pos_sims[(size_t)(g * 8 + t) * 8 + idx] = v;
            ++idx;
        }
        min_pos[g * 8 + t] = mn;
    }
}

// ---------------- K2: fp8 MFMA sim tiles; depth-6 per-wave DMA ring ----------
// grid 2080 x 64 threads, 1-wave blocks, no barriers. 24KB LDS ring -> 6 blocks/CU,
// 24 outstanding 1KB DMAs per wave (192 cache lines in flight). Counted waits
// retire exactly one 4-load stage per iteration (vmcnt(20) steady).
__global__ __launch_bounds__(64, 2) void k_neg(const unsigned long* __restrict__ xn8,
                                               const float* __restrict__ min_pos,
                                               float* __restrict__ sum_part,
                                               int* __restrict__ cnt_part,
                                               float* __restrict__ max_part,
                                               unsigned* __restrict__ gmax) {
    __shared__ char sbuf[6][4096];   // [stage][A 2KB | B 2KB] = 24 KB

    // decode triangular tile index (rt, ct), ct >= rt, over 64 bands
    int bid = blockIdx.x;
    int rt = 0, rem = bid;
    while (rem >= NB - rt) { rem -= NB - rt; ++rt; }
    int ct = rt + rem;
    bool diag = (rt == ct);

    int R0 = rt * 64, C0 = ct * 64;
    int l = threadIdx.x;
    int lrow = l & 15;
    int kgrp = l >> 4;

    float mA = min_pos[R0 + l];
    float mB = min_pos[C0 + l];
    asm volatile("s_waitcnt vmcnt(0)" ::: "memory");   // exact vmcnt bookkeeping below

    const char* xb = (const char*)xn8;
    const char* gA = xb + (size_t)rt * 65536 + (size_t)l * 16;
    const char* gB = xb + (size_t)ct * 65536 + (size_t)l * 16;

    #define STAGE(s_)                                                   \
        do {                                                            \
            char* d_ = sbuf[(s_) % 6];                                  \
            gld16(gA + (size_t)(s_) * 2048,        d_);                 \
            gld16(gA + (size_t)(s_) * 2048 + 1024, d_ + 1024);          \
            gld16(gB + (size_t)(s_) * 2048,        d_ + 2048);          \
            gld16(gB + (size_t)(s_) * 2048 + 1024, d_ + 3072);          \
        } while (0)

    STAGE(0); STAGE(1); STAGE(2); STAGE(3); STAGE(4); STAGE(5);

    f32x4 zero = {0.f, 0.f, 0.f, 0.f};
    f32x4 acc[4][4];
    #pragma unroll
    for (int m = 0; m < 4; ++m)
        #pragma unroll
        for (int n = 0; n < 4; ++n) acc[m][n] = zero;

    for (int it = 0; it < 32; ++it) {
        // retire stage `it` (4 loads); keep 5 stages (20 loads) in flight
        if (it <= 26)      asm volatile("s_waitcnt vmcnt(20)" ::: "memory");
        else if (it == 27) asm volatile("s_waitcnt vmcnt(16)" ::: "memory");
        else if (it == 28) asm volatile("s_waitcnt vmcnt(12)" ::: "memory");
        else if (it == 29) asm volatile("s_waitcnt vmcnt(8)"  ::: "memory");
        else if (it == 30) asm volatile("s_waitcnt vmcnt(4)"  ::: "memory");
        else               asm volatile("s_waitcnt vmcnt(0)"  ::: "memory");

        const char* buf = sbuf[it % 6];
        long a[4], b[4];
        #pragma unroll
        for (int m = 0; m < 4; ++m) {
            a[m] = *(const long*)(buf + m * 512 + l * 8);
            b[m] = *(const long*)(buf + 2048 + m * 512 + l * 8);
        }

        // MFMAs overlap ds_read returns (compiler inserts partial lgkm waits)
        #pragma unroll
        for (int m = 0; m < 4; ++m)
            #pragma unroll
            for (int n = 0; n < 4; ++n)
                acc[m][n] = __builtin_amdgcn_mfma_f32_16x16x32_fp8_fp8(
                    a[m], b[n], acc[m][n], 0, 0, 0);

        // all reads of buf consumed -> safe to overwrite its ring slot
        asm volatile("s_waitcnt lgkmcnt(0)" ::: "memory");
        if (it <= 25) STAGE(it + 6);
    }
    #undef STAGE

    // ---- epilogue: row-band stats; col-band (transpose) stats for off-diag ----
    float allmax = -1e30f;

    float thB[4];
    #pragma unroll
    for (int n = 0; n < 4; ++n) thB[n] = __shfl(mB, n * 16 + lrow) - 0.05f;

    float colS[4] = {0.f, 0.f, 0.f, 0.f};
    float colM[4] = {-1e30f, -1e30f, -1e30f, -1e30f};
    int   colC[4] = {0, 0, 0, 0};

    #pragma unroll
    for (int m = 0; m < 4; ++m) {
        #pragma unroll
        for (int reg = 0; reg < 4; ++reg) {
            int lr = m * 16 + kgrp * 4 + reg;   // local row in [0,64)
            int grow = R0 + lr;
            float th = __shfl(mA, lr) - 0.05f;
            int gi = grow >> 3;
            float rs = 0.f, rm = -1e30f;
            int rc = 0;
            #pragma unroll
            for (int n = 0; n < 4; ++n) {
                int gcol = C0 + n * 16 + lrow;
                float s = acc[m][n][reg];
                allmax = fmaxf(allmax, s);
                if ((gcol >> 3) != gi) {
                    float e = softplus(ALPHA * (s - MARGIN));
                    rm = fmaxf(rm, s);
                    if (s > th) { rs += e; rc += 1; }
                    if (!diag) {
                        colM[n] = fmaxf(colM[n], s);
                        if (s > thB[n]) { colS[n] += e; colC[n] += 1; }
                    }
                }
            }
            #pragma unroll
            for (int off = 1; off < 16; off <<= 1) {
                rs += __shfl_xor(rs, off);
                rc += __shfl_xor(rc, off);
                rm = fmaxf(rm, __shfl_xor(rm, off));
            }
            if (lrow == 0) {
                sum_part[(size_t)grow * 64 + ct] = rs;
                cnt_part[(size_t)grow * 64 + ct] = rc;
                max_part[(size_t)grow * 64 + ct] = rm;
            }
        }
    }

    if (!diag) {
        #pragma unroll
        for (int n = 0; n < 4; ++n) {
            float cs = colS[n], cm = colM[n];
            int cc = colC[n];
            cs += __shfl_xor(cs, 16); cs += __shfl_xor(cs, 32);
            cc += __shfl_xor(cc, 16); cc += __shfl_xor(cc, 32);
            cm = fmaxf(cm, __shfl_xor(cm, 16));
            cm = fmaxf(cm, __shfl_xor(cm, 32));
            if (kgrp == 0) {
                int gcol = C0 + n * 16 + lrow;
                sum_part[(size_t)gcol * 64 + rt] = cs;
                cnt_part[(size_t)gcol * 64 + rt] = cc;
                max_part[(size_t)gcol * 64 + rt] = cm;
            }
        }
    }

    #pragma unroll
    for (int off = 1; off < 64; off <<= 1) allmax = fmaxf(allmax, __shfl_xor(allmax, off));
    if (l == 0) atomicMax(gmax, fkey(allmax));
}

// ---------------- K3: per-row combine (64 slots/row) + spread-atomic final mean ----------------
__global__ __launch_bounds__(256) void k_rowfinal(const float* __restrict__ sum_part,
                                                  const int* __restrict__ cnt_part,
                                                  const float* __restrict__ max_part,
                                                  const float* __restrict__ pos_sims,
                                                  const float* __restrict__ min_pos,
                                                  const unsigned* __restrict__ gmax,
                                                  float* __restrict__ accum,
                                                  unsigned* __restrict__ cnt,
                                                  float* __restrict__ out) {
    __shared__ float sloss[4];
    int row = blockIdx.x * 4 + (threadIdx.x >> 6);
    int lane = threadIdx.x & 63;
    float ns = sum_part[(size_t)row * 64 + lane];
    int nc = cnt_part[(size_t)row * 64 + lane];
    float nm = max_part[(size_t)row * 64 + lane];
    #pragma unroll
    for (int off = 1; off < 64; off <<= 1) {
        ns += __shfl_xor(ns, off);
        nc += __shfl_xor(nc, off);
        nm = fmaxf(nm, __shfl_xor(nm, off));
    }
    if (lane == 0) {
        float base = fmaxf(fdec(*gmax) - 0.1f, MARGIN + 0.2f);
        float neg_loss = (nc > 0) ? ns / (float)nc : softplus(ALPHA * (nm - MARGIN));
        float ps = 0.f;
        int pcnt = 0;
        float mn = min_pos[row];
        #pragma unroll
        for (int i = 0; i < NINST - 1; ++i) {
            float s = pos_sims[(size_t)row * 8 + i];
            if (s < base) { ps += softplus(-2.0f * (s - MARGIN)); pcnt++; }
        }
        float pos_loss = (pcnt > 0) ? ps / (float)pcnt : softplus(-2.0f * (mn - MARGIN));
        sloss[threadIdx.x >> 6] = pos_loss + neg_loss;
    }
    __syncthreads();
    if (threadIdx.x == 0) {
        float bs = sloss[0] + sloss[1] + sloss[2] + sloss[3];
        atomicAdd(&accum[blockIdx.x & 31], bs);
        __threadfence();
        unsigned old = atomicAdd(cnt, 1u);
        if (old == gridDim.x - 1) {
            __threadfence();
            float tot = 0.f;
            for (int j = 0; j < 32; ++j) tot += atomicAdd(&accum[j], 0.0f);
            out[0] = tot / (float)N;
        }
    }
}

extern "C" void kernel_launch(void* const* d_in, const int* in_sizes, int n_in,
                              void* d_out, int out_size, void* d_ws, size_t ws_size,
                              hipStream_t stream) {
    const float* in = (const float*)d_in[0];
    float* out = (float*)d_out;

    char* ws = (char*)d_ws;
    unsigned long* xn8 = (unsigned long*)(ws);                  // 4 MB (banded fragment-major)
    float*   min_pos  = (float*)(ws + 8388608 + 16384);         // 16 KB
    float*   pos_sims = (float*)(ws + 8388608 + 32768);         // 128 KB
    float*   sum_part = (float*)(ws + 8388608 + 32768 + 131072);            // 1 MB
    float*   max_part = (float*)(ws + 8388608 + 32768 + 131072 + 1048576);  // 1 MB
    int*     cnt_part = (int*)  (ws + 8388608 + 32768 + 131072 + 2097152);  // 1 MB
    unsigned* gmax    = (unsigned*)(ws + 8388608 + 32768 + 131072 + 3145728);
    float*   accum    = (float*)(ws + 8388608 + 32768 + 131072 + 3145728 + 128);  // 32 floats
    unsigned* cnt     = (unsigned*)(ws + 8388608 + 32768 + 131072 + 3145728 + 256);

    k_normpos<<<NGROUP, 256, 0, stream>>>(in, xn8, pos_sims, min_pos, gmax, accum, cnt);
    k_neg<<<NTILE, 64, 0, stream>>>(xn8, min_pos, sum_part, cnt_part, max_part, gmax);
    k_rowfinal<<<N / 4, 256, 0, stream>>>(sum_part, cnt_part, max_part, pos_sims, min_pos,
                                          gmax, accum, cnt, out);
}

// Round 15
// 107.864 us; speedup vs baseline: 4.3281x; 1.0912x over previous
//
#include <hip/hip_runtime.h>
#include <hip/hip_bf16.h>
#include <hip/hip_fp8.h>
#include <math.h>

#define N 4096
#define D 1024
#define NINST 8
#define NGROUP (N / NINST)
#define ALPHA 20.0f
#define MARGIN 0.5f
#define NB 64            // 64-row bands
#define NTILE (NB * (NB + 1) / 2)   // 2080 triangular tiles

typedef __attribute__((ext_vector_type(4))) float f32x4;

__device__ __forceinline__ unsigned fkey(float f) {
    int b = __float_as_int(f);
    return (b >= 0) ? ((unsigned)b | 0x80000000u) : ~(unsigned)b;
}
__device__ __forceinline__ float fdec(unsigned u) {
    int b = (u & 0x80000000u) ? (int)(u ^ 0x80000000u) : ~(int)u;
    return __int_as_float(b);
}

// stable fast softplus: log1p(exp(x)) = max(x,0) + log(1 + exp(-|x|))
__device__ __forceinline__ float softplus(float x) {
    float z = __expf(-fabsf(x));
    return fmaxf(x, 0.0f) + __logf(1.0f + z);
}

// async global -> LDS, 16 bytes per lane (lds dest: wave-uniform base + lane*16)
__device__ __forceinline__ void gld16(const void* g, void* l) {
    __builtin_amdgcn_global_load_lds(
        (const __attribute__((address_space(1))) void*)g,
        (__attribute__((address_space(3))) void*)l, 16, 0, 0);
}

// ---------------- K1: per-group normalize + banded fragment-major fp8 write + fp32 Gram ----
// xn8 layout (ulong units): idx = band*8192 + kstep*256 + m*64 + slot, where
// band = row>>6, m = (row>>4)&3, slot = oct*16 + (row&15); the ulong holds row's
// fp8 bytes [kstep*32 + oct*8, +8). One (band,kstep) panel = 2KB contiguous.
__global__ __launch_bounds__(256) void k_normpos(const float* __restrict__ in,
                                                 unsigned long* __restrict__ xn8,
                                                 float* __restrict__ pos_sims,
                                                 float* __restrict__ min_pos,
                                                 unsigned* __restrict__ gmax,
                                                 float* __restrict__ accum,
                                                 unsigned* __restrict__ cnt) {
    __shared__ float4 srows4[8 * 257];   // padded stride: no Gram bank conflicts
    __shared__ float spart[8][4];
    __shared__ float sinv[8];
    __shared__ float sg[8][8];

    int g = blockIdx.x;
    int t = threadIdx.x;
    int lane = t & 63, wid = t >> 6;

    if (g == 0) {
        if (t == 0) { *gmax = 0u; *cnt = 0u; }
        if (t < 32) accum[t] = 0.f;
    }

    const float4* in4 = (const float4*)in;
    #pragma unroll
    for (int i = 0; i < 8; ++i) {
        float4 v = in4[(size_t)g * 2048 + i * 256 + t];
        srows4[i * 257 + t] = v;
        float ss = v.x * v.x + v.y * v.y + v.z * v.z + v.w * v.w;
        #pragma unroll
        for (int off = 1; off < 64; off <<= 1) ss += __shfl_xor(ss, off);
        if (lane == 0) spart[i][wid] = ss;
    }
    __syncthreads();
    if (t < 8) sinv[t] = rsqrtf(spart[t][0] + spart[t][1] + spart[t][2] + spart[t][3]);
    __syncthreads();

    // fragment-major fp8 write: 4 ulong slots per thread
    {
        int i_row = t & 7;              // local row 0..7
        int oct  = (t >> 3) & 3;        // k-octet
        int k0b  = t >> 5;              // 0..7
        size_t base = (size_t)(g >> 3) * 8192 + (size_t)((g >> 1) & 3) * 64
                    + (size_t)(oct * 16 + (g & 1) * 8 + i_row);
        float inv = sinv[i_row];
        #pragma unroll
        for (int j = 0; j < 4; ++j) {
            int k0 = k0b + j * 8;       // 0..31
            float4 v0 = srows4[i_row * 257 + k0 * 8 + oct * 2];
            float4 v1 = srows4[i_row * 257 + k0 * 8 + oct * 2 + 1];
            union { unsigned char c[8]; unsigned long u64; } o;
            o.c[0] = __hip_fp8_e4m3(v0.x * inv).__x;
            o.c[1] = __hip_fp8_e4m3(v0.y * inv).__x;
            o.c[2] = __hip_fp8_e4m3(v0.z * inv).__x;
            o.c[3] = __hip_fp8_e4m3(v0.w * inv).__x;
            o.c[4] = __hip_fp8_e4m3(v1.x * inv).__x;
            o.c[5] = __hip_fp8_e4m3(v1.y * inv).__x;
            o.c[6] = __hip_fp8_e4m3(v1.z * inv).__x;
            o.c[7] = __hip_fp8_e4m3(v1.w * inv).__x;
            xn8[base + (size_t)k0 * 256] = o.u64;
        }
    }

    int pair = t >> 2, a = pair >> 3, b = pair & 7, slice = t & 3;
    const float4* pa = srows4 + a * 257 + slice * 64;
    const float4* pb = srows4 + b * 257 + slice * 64;
    float s = 0.f;
    #pragma unroll 8
    for (int i = 0; i < 64; ++i) {
        float4 x = pa[i], y = pb[i];
        s += x.x * y.x + x.y * y.y + x.z * y.z + x.w * y.w;
    }
    s += __shfl_xor(s, 1);
    s += __shfl_xor(s, 2);
    if (slice == 0) sg[a][b] = s * sinv[a] * sinv[b];
    __syncthreads();
    if (t < 8) {
        float mn = 1e30f;
        int idx = 0;
        #pragma unroll
        for (int b2 = 0; b2 < 8; ++b2) {
            if (b2 == t) continue;
            float v = sg[t][b2];
            mn = fminf(mn, v);
            pos_sims[(size_t)(g * 8 + t) * 8 + idx] = v;
            ++idx;
        }
        min_pos[g * 8 + t] = mn;
    }
}

// ---------------- K2: fp8 MFMA sim tiles; 8 independent tile-waves per block ----------
// grid 260 x 512 threads = 2080 tile-waves exactly; NO barriers. Per wave: private
// depth-2 LDS ring (8 KB; 64 KB/block -> 2 blocks/CU = 16 waves/CU capacity).
// Per k-step: counted vmcnt(4) -> 8 ds_read_b64 -> 16 MFMA -> lgkm(0) -> re-stage.
__global__ __launch_bounds__(512, 4) void k_neg(const unsigned long* __restrict__ xn8,
                                                const float* __restrict__ min_pos,
                                                float* __restrict__ sum_part,
                                                int* __restrict__ cnt_part,
                                                float* __restrict__ max_part,
                                                unsigned* __restrict__ gmax) {
    __shared__ char sbuf[8][2][4096];   // [wave][stage][A 2KB | B 2KB] = 64 KB

    int t = threadIdx.x;
    int w = t >> 6;               // wave id 0..7
    int l = t & 63;
    int u = blockIdx.x * 8 + w;   // tile unit 0..2079 (exact)

    // decode triangular tile index (rt, ct), ct >= rt, over 64 bands
    int rt = 0, rem = u;
    while (rem >= NB - rt) { rem -= NB - rt; ++rt; }
    int ct = rt + rem;
    bool diag = (rt == ct);

    int R0 = rt * 64, C0 = ct * 64;
    int lrow = l & 15;
    int kgrp = l >> 4;

    float mA = min_pos[R0 + l];
    float mB = min_pos[C0 + l];
    asm volatile("s_waitcnt vmcnt(0)" ::: "memory");   // exact vmcnt bookkeeping below

    const char* xb = (const char*)xn8;
    const char* gA = xb + (size_t)rt * 65536 + (size_t)l * 16;
    const char* gB = xb + (size_t)ct * 65536 + (size_t)l * 16;
    char* ring = &sbuf[w][0][0];

    #define STAGE(s_)                                                   \
        do {                                                            \
            char* d_ = ring + ((s_) & 1) * 4096;                        \
            gld16(gA + (size_t)(s_) * 2048,        d_);                 \
            gld16(gA + (size_t)(s_) * 2048 + 1024, d_ + 1024);          \
            gld16(gB + (size_t)(s_) * 2048,        d_ + 2048);          \
            gld16(gB + (size_t)(s_) * 2048 + 1024, d_ + 3072);          \
        } while (0)

    STAGE(0); STAGE(1);

    f32x4 zero = {0.f, 0.f, 0.f, 0.f};
    f32x4 acc[4][4];
    #pragma unroll
    for (int m = 0; m < 4; ++m)
        #pragma unroll
        for (int n = 0; n < 4; ++n) acc[m][n] = zero;

    for (int it = 0; it < 32; ++it) {
        // retire stage `it` (4 loads); stage it+1 stays in flight
        if (it <= 30) asm volatile("s_waitcnt vmcnt(4)" ::: "memory");
        else          asm volatile("s_waitcnt vmcnt(0)" ::: "memory");

        const char* buf = ring + (it & 1) * 4096;
        long a[4], b[4];
        #pragma unroll
        for (int m = 0; m < 4; ++m) {
            a[m] = *(const long*)(buf + m * 512 + l * 8);
            b[m] = *(const long*)(buf + 2048 + m * 512 + l * 8);
        }

        // MFMAs overlap ds_read returns (compiler inserts partial lgkm waits)
        #pragma unroll
        for (int m = 0; m < 4; ++m)
            #pragma unroll
            for (int n = 0; n < 4; ++n)
                acc[m][n] = __builtin_amdgcn_mfma_f32_16x16x32_fp8_fp8(
                    a[m], b[n], acc[m][n], 0, 0, 0);

        // all reads of buf consumed -> safe to overwrite its ring slot
        asm volatile("s_waitcnt lgkmcnt(0)" ::: "memory");
        if (it <= 29) STAGE(it + 2);
    }
    #undef STAGE

    // ---- epilogue: row-band stats; col-band (transpose) stats for off-diag ----
    float allmax = -1e30f;

    float thB[4];
    #pragma unroll
    for (int n = 0; n < 4; ++n) thB[n] = __shfl(mB, n * 16 + lrow) - 0.05f;

    float colS[4] = {0.f, 0.f, 0.f, 0.f};
    float colM[4] = {-1e30f, -1e30f, -1e30f, -1e30f};
    int   colC[4] = {0, 0, 0, 0};

    #pragma unroll
    for (int m = 0; m < 4; ++m) {
        #pragma unroll
        for (int reg = 0; reg < 4; ++reg) {
            int lr = m * 16 + kgrp * 4 + reg;   // local row in [0,64)
            int grow = R0 + lr;
            float th = __shfl(mA, lr) - 0.05f;
            int gi = grow >> 3;
            float rs = 0.f, rm = -1e30f;
            int rc = 0;
            #pragma unroll
            for (int n = 0; n < 4; ++n) {
                int gcol = C0 + n * 16 + lrow;
                float s = acc[m][n][reg];
                allmax = fmaxf(allmax, s);
                if ((gcol >> 3) != gi) {
                    float e = softplus(ALPHA * (s - MARGIN));
                    rm = fmaxf(rm, s);
                    if (s > th) { rs += e; rc += 1; }
                    if (!diag) {
                        colM[n] = fmaxf(colM[n], s);
                        if (s > thB[n]) { colS[n] += e; colC[n] += 1; }
                    }
                }
            }
            #pragma unroll
            for (int off = 1; off < 16; off <<= 1) {
                rs += __shfl_xor(rs, off);
                rc += __shfl_xor(rc, off);
                rm = fmaxf(rm, __shfl_xor(rm, off));
            }
            if (lrow == 0) {
                sum_part[(size_t)grow * 64 + ct] = rs;
                cnt_part[(size_t)grow * 64 + ct] = rc;
                max_part[(size_t)grow * 64 + ct] = rm;
            }
        }
    }

    if (!diag) {
        #pragma unroll
        for (int n = 0; n < 4; ++n) {
            float cs = colS[n], cm = colM[n];
            int cc = colC[n];
            cs += __shfl_xor(cs, 16); cs += __shfl_xor(cs, 32);
            cc += __shfl_xor(cc, 16); cc += __shfl_xor(cc, 32);
            cm = fmaxf(cm, __shfl_xor(cm, 16));
            cm = fmaxf(cm, __shfl_xor(cm, 32));
            if (kgrp == 0) {
                int gcol = C0 + n * 16 + lrow;
                sum_part[(size_t)gcol * 64 + rt] = cs;
                cnt_part[(size_t)gcol * 64 + rt] = cc;
                max_part[(size_t)gcol * 64 + rt] = cm;
            }
        }
    }

    #pragma unroll
    for (int off = 1; off < 64; off <<= 1) allmax = fmaxf(allmax, __shfl_xor(allmax, off));
    if (l == 0) atomicMax(gmax, fkey(allmax));
}

// ---------------- K3: per-row combine (64 slots/row) + spread-atomic final mean ----------------
__global__ __launch_bounds__(256) void k_rowfinal(const float* __restrict__ sum_part,
                                                  const int* __restrict__ cnt_part,
                                                  const float* __restrict__ max_part,
                                                  const float* __restrict__ pos_sims,
                                                  const float* __restrict__ min_pos,
                                                  const unsigned* __restrict__ gmax,
                                                  float* __restrict__ accum,
                                                  unsigned* __restrict__ cnt,
                                                  float* __restrict__ out) {
    __shared__ float sloss[4];
    int row = blockIdx.x * 4 + (threadIdx.x >> 6);
    int lane = threadIdx.x & 63;
    float ns = sum_part[(size_t)row * 64 + lane];
    int nc = cnt_part[(size_t)row * 64 + lane];
    float nm = max_part[(size_t)row * 64 + lane];
    #pragma unroll
    for (int off = 1; off < 64; off <<= 1) {
        ns += __shfl_xor(ns, off);
        nc += __shfl_xor(nc, off);
        nm = fmaxf(nm, __shfl_xor(nm, off));
    }
    if (lane == 0) {
        float base = fmaxf(fdec(*gmax) - 0.1f, MARGIN + 0.2f);
        float neg_loss = (nc > 0) ? ns / (float)nc : softplus(ALPHA * (nm - MARGIN));
        float ps = 0.f;
        int pcnt = 0;
        float mn = min_pos[row];
        #pragma unroll
        for (int i = 0; i < NINST - 1; ++i) {
            float s = pos_sims[(size_t)row * 8 + i];
            if (s < base) { ps += softplus(-2.0f * (s - MARGIN)); pcnt++; }
        }
        float pos_loss = (pcnt > 0) ? ps / (float)pcnt : softplus(-2.0f * (mn - MARGIN));
        sloss[threadIdx.x >> 6] = pos_loss + neg_loss;
    }
    __syncthreads();
    if (threadIdx.x == 0) {
        float bs = sloss[0] + sloss[1] + sloss[2] + sloss[3];
        atomicAdd(&accum[blockIdx.x & 31], bs);
        __threadfence();
        unsigned old = atomicAdd(cnt, 1u);
        if (old == gridDim.x - 1) {
            __threadfence();
            float tot = 0.f;
            for (int j = 0; j < 32; ++j) tot += atomicAdd(&accum[j], 0.0f);
            out[0] = tot / (float)N;
        }
    }
}

extern "C" void kernel_launch(void* const* d_in, const int* in_sizes, int n_in,
                              void* d_out, int out_size, void* d_ws, size_t ws_size,
                              hipStream_t stream) {
    const float* in = (const float*)d_in[0];
    float* out = (float*)d_out;

    char* ws = (char*)d_ws;
    unsigned long* xn8 = (unsigned long*)(ws);                  // 4 MB (banded fragment-major)
    float*   min_pos  = (float*)(ws + 8388608 + 16384);         // 16 KB
    float*   pos_sims = (float*)(ws + 8388608 + 32768);         // 128 KB
    float*   sum_part = (float*)(ws + 8388608 + 32768 + 131072);            // 1 MB
    float*   max_part = (float*)(ws + 8388608 + 32768 + 131072 + 1048576);  // 1 MB
    int*     cnt_part = (int*)  (ws + 8388608 + 32768 + 131072 + 2097152);  // 1 MB
    unsigned* gmax    = (unsigned*)(ws + 8388608 + 32768 + 131072 + 3145728);
    float*   accum    = (float*)(ws + 8388608 + 32768 + 131072 + 3145728 + 128);  // 32 floats
    unsigned* cnt     = (unsigned*)(ws + 8388608 + 32768 + 131072 + 3145728 + 256);

    k_normpos<<<NGROUP, 256, 0, stream>>>(in, xn8, pos_sims, min_pos, gmax, accum, cnt);
    k_neg<<<NTILE / 8, 512, 0, stream>>>(xn8, min_pos, sum_part, cnt_part, max_part, gmax);
    k_rowfinal<<<N / 4, 256, 0, stream>>>(sum_part, cnt_part, max_part, pos_sims, min_pos,
                                          gmax, accum, cnt, out);
}

// Round 16
// 100.127 us; speedup vs baseline: 4.6626x; 1.0773x over previous
//
#include <hip/hip_runtime.h>
#include <hip/hip_bf16.h>
#include <hip/hip_fp8.h>
#include <math.h>

#define N 4096
#define D 1024
#define NINST 8
#define NGROUP (N / NINST)
#define ALPHA 20.0f
#define MARGIN 0.5f
#define NB 64            // 64-row bands
#define NTILE (NB * (NB + 1) / 2)   // 2080 triangular tiles

typedef __attribute__((ext_vector_type(4))) float f32x4;

__device__ __forceinline__ unsigned fkey(float f) {
    int b = __float_as_int(f);
    return (b >= 0) ? ((unsigned)b | 0x80000000u) : ~(unsigned)b;
}
__device__ __forceinline__ float fdec(unsigned u) {
    int b = (u & 0x80000000u) ? (int)(u ^ 0x80000000u) : ~(int)u;
    return __int_as_float(b);
}

// stable fast softplus: log1p(exp(x)) = max(x,0) + log(1 + exp(-|x|))
__device__ __forceinline__ float softplus(float x) {
    float z = __expf(-fabsf(x));
    return fmaxf(x, 0.0f) + __logf(1.0f + z);
}

// async global -> LDS, 16 bytes per lane (lds dest: wave-uniform base + lane*16)
__device__ __forceinline__ void gld16(const void* g, void* l) {
    __builtin_amdgcn_global_load_lds(
        (const __attribute__((address_space(1))) void*)g,
        (__attribute__((address_space(3))) void*)l, 16, 0, 0);
}

// ---------------- K1: per-group normalize + banded fragment-major fp8 write + fp32 Gram ----
// xn8 layout (ulong units): idx = band*8192 + kstep*256 + m*64 + slot, where
// band = row>>6, m = (row>>4)&3, slot = oct*16 + (row&15); the ulong holds row's
// fp8 bytes [kstep*32 + oct*8, +8). One (band,kstep) panel = 2KB contiguous.
// Gram reads staggered by (pair + 2*slice): uniform bank classes (was 32-lane collision).
__global__ __launch_bounds__(256) void k_normpos(const float* __restrict__ in,
                                                 unsigned long* __restrict__ xn8,
                                                 float* __restrict__ pos_sims,
                                                 float* __restrict__ min_pos,
                                                 unsigned* __restrict__ gmax,
                                                 float* __restrict__ accum,
                                                 unsigned* __restrict__ cnt) {
    __shared__ float4 srows4[8 * 257];   // padded stride
    __shared__ float spart[8][4];
    __shared__ float sinv[8];
    __shared__ float sg[8][8];

    int g = blockIdx.x;
    int t = threadIdx.x;
    int lane = t & 63, wid = t >> 6;

    if (g == 0) {
        if (t == 0) { *gmax = 0u; *cnt = 0u; }
        if (t < 32) accum[t] = 0.f;
    }

    const float4* in4 = (const float4*)in;
    #pragma unroll
    for (int i = 0; i < 8; ++i) {
        float4 v = in4[(size_t)g * 2048 + i * 256 + t];
        srows4[i * 257 + t] = v;
        float ss = v.x * v.x + v.y * v.y + v.z * v.z + v.w * v.w;
        #pragma unroll
        for (int off = 1; off < 64; off <<= 1) ss += __shfl_xor(ss, off);
        if (lane == 0) spart[i][wid] = ss;
    }
    __syncthreads();
    if (t < 8) sinv[t] = rsqrtf(spart[t][0] + spart[t][1] + spart[t][2] + spart[t][3]);
    __syncthreads();

    // fragment-major fp8 write: 4 ulong slots per thread (bank classes uniform)
    {
        int i_row = t & 7;              // local row 0..7
        int oct  = (t >> 3) & 3;        // k-octet
        int k0b  = t >> 5;              // 0..7
        size_t base = (size_t)(g >> 3) * 8192 + (size_t)((g >> 1) & 3) * 64
                    + (size_t)(oct * 16 + (g & 1) * 8 + i_row);
        float inv = sinv[i_row];
        #pragma unroll
        for (int j = 0; j < 4; ++j) {
            int k0 = k0b + j * 8;       // 0..31
            float4 v0 = srows4[i_row * 257 + k0 * 8 + oct * 2];
            float4 v1 = srows4[i_row * 257 + k0 * 8 + oct * 2 + 1];
            union { unsigned char c[8]; unsigned long u64; } o;
            o.c[0] = __hip_fp8_e4m3(v0.x * inv).__x;
            o.c[1] = __hip_fp8_e4m3(v0.y * inv).__x;
            o.c[2] = __hip_fp8_e4m3(v0.z * inv).__x;
            o.c[3] = __hip_fp8_e4m3(v0.w * inv).__x;
            o.c[4] = __hip_fp8_e4m3(v1.x * inv).__x;
            o.c[5] = __hip_fp8_e4m3(v1.y * inv).__x;
            o.c[6] = __hip_fp8_e4m3(v1.z * inv).__x;
            o.c[7] = __hip_fp8_e4m3(v1.w * inv).__x;
            xn8[base + (size_t)k0 * 256] = o.u64;
        }
    }

    // Gram: 64 pairs x 4 D-slices; start index staggered per (pair,slice)
    int pair = t >> 2, a = pair >> 3, b = pair & 7, slice = t & 3;
    const float4* pa = srows4 + a * 257 + slice * 64;
    const float4* pb = srows4 + b * 257 + slice * 64;
    int j0 = (pair + slice * 2) & 63;
    float s = 0.f;
    #pragma unroll 8
    for (int i = 0; i < 64; ++i) {
        int j = (i + j0) & 63;
        float4 x = pa[j], y = pb[j];
        s += x.x * y.x + x.y * y.y + x.z * y.z + x.w * y.w;
    }
    s += __shfl_xor(s, 1);
    s += __shfl_xor(s, 2);
    if (slice == 0) sg[a][b] = s * sinv[a] * sinv[b];
    __syncthreads();
    if (t < 8) {
        float mn = 1e30f;
        int idx = 0;
        #pragma unroll
        for (int b2 = 0; b2 < 8; ++b2) {
            if (b2 == t) continue;
            float v = sg[t][b2];
            mn = fminf(mn, v);
            pos_sims[(size_t)(g * 8 + t) * 8 + idx] = v;
            ++idx;
        }
        min_pos[g * 8 + t] = mn;
    }
}

// ---------------- K2: fp8 MFMA sim tiles; 4 independent tile-waves per block ----------
// (R12 best-known config, unchanged.) grid 520 x 256 threads = 2080 tile-waves; NO
// barriers. Per wave: private depth-3 LDS ring (12 KB); per k-step: counted vmcnt(8)
// -> 8 ds_read_b64 -> 16 MFMA -> lgkm(0) -> re-stage just-read buffer.
__global__ __launch_bounds__(256, 2) void k_neg(const unsigned long* __restrict__ xn8,
                                                const float* __restrict__ min_pos,
                                                float* __restrict__ sum_part,
                                                int* __restrict__ cnt_part,
                                                float* __restrict__ max_part,
                                                unsigned* __restrict__ gmax) {
    __shared__ char sbuf[4][3][4096];   // [wave][stage][A 2KB | B 2KB] = 48 KB

    int t = threadIdx.x;
    int w = t >> 6;          // wave id 0..3
    int l = t & 63;
    int u = blockIdx.x * 4 + w;   // tile unit 0..2079

    // decode triangular tile index (rt, ct), ct >= rt, over 64 bands
    int rt = 0, rem = u;
    while (rem >= NB - rt) { rem -= NB - rt; ++rt; }
    int ct = rt + rem;
    bool diag = (rt == ct);

    int R0 = rt * 64, C0 = ct * 64;
    int lrow = l & 15;
    int kgrp = l >> 4;

    float mA = min_pos[R0 + l];
    float mB = min_pos[C0 + l];
    asm volatile("s_waitcnt vmcnt(0)" ::: "memory");   // exact vmcnt bookkeeping below

    const char* xb = (const char*)xn8;
    const char* gA = xb + (size_t)rt * 65536 + (size_t)l * 16;
    const char* gB = xb + (size_t)ct * 65536 + (size_t)l * 16;
    char* ring = &sbuf[w][0][0];

    #define STAGE(s_)                                                   \
        do {                                                            \
            char* d_ = ring + ((s_) % 3) * 4096;                        \
            gld16(gA + (size_t)(s_) * 2048,        d_);                 \
            gld16(gA + (size_t)(s_) * 2048 + 1024, d_ + 1024);          \
            gld16(gB + (size_t)(s_) * 2048,        d_ + 2048);          \
            gld16(gB + (size_t)(s_) * 2048 + 1024, d_ + 3072);          \
        } while (0)

    STAGE(0); STAGE(1); STAGE(2);

    f32x4 zero = {0.f, 0.f, 0.f, 0.f};
    f32x4 acc[4][4];
    #pragma unroll
    for (int m = 0; m < 4; ++m)
        #pragma unroll
        for (int n = 0; n < 4; ++n) acc[m][n] = zero;

    for (int it = 0; it < 32; ++it) {
        // retire stage `it` (4 loads); keep up to 2 stages in flight
        if (it <= 29)      asm volatile("s_waitcnt vmcnt(8)" ::: "memory");
        else if (it == 30) asm volatile("s_waitcnt vmcnt(4)" ::: "memory");
        else               asm volatile("s_waitcnt vmcnt(0)" ::: "memory");

        const char* buf = ring + (it % 3) * 4096;
        long a[4], b[4];
        #pragma unroll
        for (int m = 0; m < 4; ++m) {
            a[m] = *(const long*)(buf + m * 512 + l * 8);
            b[m] = *(const long*)(buf + 2048 + m * 512 + l * 8);
        }

        // MFMAs overlap ds_read returns (compiler inserts partial lgkm waits)
        #pragma unroll
        for (int m = 0; m < 4; ++m)
            #pragma unroll
            for (int n = 0; n < 4; ++n)
                acc[m][n] = __builtin_amdgcn_mfma_f32_16x16x32_fp8_fp8(
                    a[m], b[n], acc[m][n], 0, 0, 0);

        // all reads of buf consumed -> safe to overwrite its ring slot
        asm volatile("s_waitcnt lgkmcnt(0)" ::: "memory");
        if (it <= 28) STAGE(it + 3);
    }
    #undef STAGE

    // ---- epilogue: row-band stats; col-band (transpose) stats for off-diag ----
    float allmax = -1e30f;

    float thB[4];
    #pragma unroll
    for (int n = 0; n < 4; ++n) thB[n] = __shfl(mB, n * 16 + lrow) - 0.05f;

    float colS[4] = {0.f, 0.f, 0.f, 0.f};
    float colM[4] = {-1e30f, -1e30f, -1e30f, -1e30f};
    int   colC[4] = {0, 0, 0, 0};

    #pragma unroll
    for (int m = 0; m < 4; ++m) {
        #pragma unroll
        for (int reg = 0; reg < 4; ++reg) {
            int lr = m * 16 + kgrp * 4 + reg;   // local row in [0,64)
            int grow = R0 + lr;
            float th = __shfl(mA, lr) - 0.05f;
            int gi = grow >> 3;
            float rs = 0.f, rm = -1e30f;
            int rc = 0;
            #pragma unroll
            for (int n = 0; n < 4; ++n) {
                int gcol = C0 + n * 16 + lrow;
                float s = acc[m][n][reg];
                allmax = fmaxf(allmax, s);
                if ((gcol >> 3) != gi) {
                    float e = softplus(ALPHA * (s - MARGIN));
                    rm = fmaxf(rm, s);
                    if (s > th) { rs += e; rc += 1; }
                    if (!diag) {
                        colM[n] = fmaxf(colM[n], s);
                        if (s > thB[n]) { colS[n] += e; colC[n] += 1; }
                    }
                }
            }
            #pragma unroll
            for (int off = 1; off < 16; off <<= 1) {
                rs += __shfl_xor(rs, off);
                rc += __shfl_xor(rc, off);
                rm = fmaxf(rm, __shfl_xor(rm, off));
            }
            if (lrow == 0) {
                sum_part[(size_t)grow * 64 + ct] = rs;
                cnt_part[(size_t)grow * 64 + ct] = rc;
                max_part[(size_t)grow * 64 + ct] = rm;
            }
        }
    }

    if (!diag) {
        #pragma unroll
        for (int n = 0; n < 4; ++n) {
            float cs = colS[n], cm = colM[n];
            int cc = colC[n];
            cs += __shfl_xor(cs, 16); cs += __shfl_xor(cs, 32);
            cc += __shfl_xor(cc, 16); cc += __shfl_xor(cc, 32);
            cm = fmaxf(cm, __shfl_xor(cm, 16));
            cm = fmaxf(cm, __shfl_xor(cm, 32));
            if (kgrp == 0) {
                int gcol = C0 + n * 16 + lrow;
                sum_part[(size_t)gcol * 64 + rt] = cs;
                cnt_part[(size_t)gcol * 64 + rt] = cc;
                max_part[(size_t)gcol * 64 + rt] = cm;
            }
        }
    }

    #pragma unroll
    for (int off = 1; off < 64; off <<= 1) allmax = fmaxf(allmax, __shfl_xor(allmax, off));
    if (l == 0) atomicMax(gmax, fkey(allmax));
}

// ---------------- K3: per-row combine (64 slots/row) + spread-atomic final mean ----------------
__global__ __launch_bounds__(256) void k_rowfinal(const float* __restrict__ sum_part,
                                                  const int* __restrict__ cnt_part,
                                                  const float* __restrict__ max_part,
                                                  const float* __restrict__ pos_sims,
                                                  const float* __restrict__ min_pos,
                                                  const unsigned* __restrict__ gmax,
                                                  float* __restrict__ accum,
                                                  unsigned* __restrict__ cnt,
                                                  float* __restrict__ out) {
    __shared__ float sloss[4];
    int row = blockIdx.x * 4 + (threadIdx.x >> 6);
    int lane = threadIdx.x & 63;
    float ns = sum_part[(size_t)row * 64 + lane];
    int nc = cnt_part[(size_t)row * 64 + lane];
    float nm = max_part[(size_t)row * 64 + lane];
    #pragma unroll
    for (int off = 1; off < 64; off <<= 1) {
        ns += __shfl_xor(ns, off);
        nc += __shfl_xor(nc, off);
        nm = fmaxf(nm, __shfl_xor(nm, off));
    }
    if (lane == 0) {
        float base = fmaxf(fdec(*gmax) - 0.1f, MARGIN + 0.2f);
        float neg_loss = (nc > 0) ? ns / (float)nc : softplus(ALPHA * (nm - MARGIN));
        float ps = 0.f;
        int pcnt = 0;
        float mn = min_pos[row];
        #pragma unroll
        for (int i = 0; i < NINST - 1; ++i) {
            float s = pos_sims[(size_t)row * 8 + i];
            if (s < base) { ps += softplus(-2.0f * (s - MARGIN)); pcnt++; }
        }
        float pos_loss = (pcnt > 0) ? ps / (float)pcnt : softplus(-2.0f * (mn - MARGIN));
        sloss[threadIdx.x >> 6] = pos_loss + neg_loss;
    }
    __syncthreads();
    if (threadIdx.x == 0) {
        float bs = sloss[0] + sloss[1] + sloss[2] + sloss[3];
        atomicAdd(&accum[blockIdx.x & 31], bs);
        __threadfence();
        unsigned old = atomicAdd(cnt, 1u);
        if (old == gridDim.x - 1) {
            __threadfence();
            float tot = 0.f;
            for (int j = 0; j < 32; ++j) tot += atomicAdd(&accum[j], 0.0f);
            out[0] = tot / (float)N;
        }
    }
}

extern "C" void kernel_launch(void* const* d_in, const int* in_sizes, int n_in,
                              void* d_out, int out_size, void* d_ws, size_t ws_size,
                              hipStream_t stream) {
    const float* in = (const float*)d_in[0];
    float* out = (float*)d_out;

    char* ws = (char*)d_ws;
    unsigned long* xn8 = (unsigned long*)(ws);                  // 4 MB (banded fragment-major)
    float*   min_pos  = (float*)(ws + 8388608 + 16384);         // 16 KB
    float*   pos_sims = (float*)(ws + 8388608 + 32768);         // 128 KB
    float*   sum_part = (float*)(ws + 8388608 + 32768 + 131072);            // 1 MB
    float*   max_part = (float*)(ws + 8388608 + 32768 + 131072 + 1048576);  // 1 MB
    int*     cnt_part = (int*)  (ws + 8388608 + 32768 + 131072 + 2097152);  // 1 MB
    unsigned* gmax    = (unsigned*)(ws + 8388608 + 32768 + 131072 + 3145728);
    float*   accum    = (float*)(ws + 8388608 + 32768 + 131072 + 3145728 + 128);  // 32 floats
    unsigned* cnt     = (unsigned*)(ws + 8388608 + 32768 + 131072 + 3145728 + 256);

    k_normpos<<<NGROUP, 256, 0, stream>>>(in, xn8, pos_sims, min_pos, gmax, accum, cnt);
    k_neg<<<NTILE / 4, 256, 0, stream>>>(xn8, min_pos, sum_part, cnt_part, max_part, gmax);
    k_rowfinal<<<N / 4, 256, 0, stream>>>(sum_part, cnt_part, max_part, pos_sims, min_pos,
                                          gmax, accum, cnt, out);
}

// Round 17
// 99.419 us; speedup vs baseline: 4.6958x; 1.0071x over previous
//
#include <hip/hip_runtime.h>
#include <hip/hip_bf16.h>
#include <hip/hip_fp8.h>
#include <math.h>

#define N 4096
#define D 1024
#define NINST 8
#define NGROUP (N / NINST)
#define ALPHA 20.0f
#define MARGIN 0.5f
#define NB 64            // 64-row bands
#define NTILE (NB * (NB + 1) / 2)   // 2080 triangular tiles

typedef __attribute__((ext_vector_type(4))) float f32x4;

__device__ __forceinline__ unsigned fkey(float f) {
    int b = __float_as_int(f);
    return (b >= 0) ? ((unsigned)b | 0x80000000u) : ~(unsigned)b;
}
__device__ __forceinline__ float fdec(unsigned u) {
    int b = (u & 0x80000000u) ? (int)(u ^ 0x80000000u) : ~(int)u;
    return __int_as_float(b);
}

// stable fast softplus: log1p(exp(x)) = max(x,0) + log(1 + exp(-|x|))
__device__ __forceinline__ float softplus(float x) {
    float z = __expf(-fabsf(x));
    return fmaxf(x, 0.0f) + __logf(1.0f + z);
}

// async global -> LDS, 16 bytes per lane (lds dest: wave-uniform base + lane*16)
__device__ __forceinline__ void gld16(const void* g, void* l) {
    __builtin_amdgcn_global_load_lds(
        (const __attribute__((address_space(1))) void*)g,
        (__attribute__((address_space(3))) void*)l, 16, 0, 0);
}

// ---------------- K1: per-group normalize + banded fragment-major fp8 write + fp32 Gram ----
// 512 threads/block (8 waves): halved serial chains vs 256-thr version.
// xn8 layout (ulong units): idx = band*8192 + kstep*256 + m*64 + slot, where
// band = row>>6, m = (row>>4)&3, slot = oct*16 + (row&15); the ulong holds row's
// fp8 bytes [kstep*32 + oct*8, +8). One (band,kstep) panel = 2KB contiguous.
__global__ __launch_bounds__(512) void k_normpos(const float* __restrict__ in,
                                                 unsigned long* __restrict__ xn8,
                                                 float* __restrict__ pos_sims,
                                                 float* __restrict__ min_pos,
                                                 unsigned* __restrict__ gmax,
                                                 float* __restrict__ accum,
                                                 unsigned* __restrict__ cnt) {
    __shared__ float4 srows4[8 * 257];   // padded stride
    __shared__ float spart[8][4];
    __shared__ float sinv[8];
    __shared__ float sg[8][8];

    int g = blockIdx.x;
    int t = threadIdx.x;          // 0..511
    int lane = t & 63;
    int w = t >> 6;               // wave 0..7
    int par = t >> 8;             // row parity 0/1

    if (g == 0) {
        if (t == 0) { *gmax = 0u; *cnt = 0u; }
        if (t < 32) accum[t] = 0.f;
    }

    // loads: 4 float4/thread; load k covers rows 2k+par, col t&255
    const float4* in4 = (const float4*)in;
    #pragma unroll
    for (int k = 0; k < 4; ++k) {
        float4 v = in4[(size_t)g * 2048 + k * 512 + t];
        int row = 2 * k + par;
        srows4[row * 257 + (t & 255)] = v;
        float ss = v.x * v.x + v.y * v.y + v.z * v.z + v.w * v.w;
        #pragma unroll
        for (int off = 1; off < 64; off <<= 1) ss += __shfl_xor(ss, off);
        if (lane == 0) spart[row][w & 3] = ss;
    }
    __syncthreads();
    if (t < 8) sinv[t] = rsqrtf(spart[t][0] + spart[t][1] + spart[t][2] + spart[t][3]);
    __syncthreads();

    // fragment-major fp8 write: 2 ulong slots per thread
    {
        int i_row = t & 7;              // local row 0..7
        int oct  = (t >> 3) & 3;        // k-octet
        int k0b  = (t >> 5) & 7;        // 0..7
        int hi   = t >> 8;              // 0/1
        size_t base = (size_t)(g >> 3) * 8192 + (size_t)((g >> 1) & 3) * 64
                    + (size_t)(oct * 16 + (g & 1) * 8 + i_row);
        float inv = sinv[i_row];
        #pragma unroll
        for (int jj = 0; jj < 2; ++jj) {
            int k0 = k0b + (hi * 2 + jj) * 8;   // 0..31
            float4 v0 = srows4[i_row * 257 + k0 * 8 + oct * 2];
            float4 v1 = srows4[i_row * 257 + k0 * 8 + oct * 2 + 1];
            union { unsigned char c[8]; unsigned long u64; } o;
            o.c[0] = __hip_fp8_e4m3(v0.x * inv).__x;
            o.c[1] = __hip_fp8_e4m3(v0.y * inv).__x;
            o.c[2] = __hip_fp8_e4m3(v0.z * inv).__x;
            o.c[3] = __hip_fp8_e4m3(v0.w * inv).__x;
            o.c[4] = __hip_fp8_e4m3(v1.x * inv).__x;
            o.c[5] = __hip_fp8_e4m3(v1.y * inv).__x;
            o.c[6] = __hip_fp8_e4m3(v1.z * inv).__x;
            o.c[7] = __hip_fp8_e4m3(v1.w * inv).__x;
            xn8[base + (size_t)k0 * 256] = o.u64;
        }
    }

    // Gram: 64 pairs x 8 slices of 32 float4; staggered start; 3-shfl reduce
    int pair = t >> 3, a = pair >> 3, b = pair & 7, slice = t & 7;
    const float4* pa = srows4 + a * 257 + slice * 32;
    const float4* pb = srows4 + b * 257 + slice * 32;
    int j0 = ((pair << 1) + slice) & 31;
    float s = 0.f;
    #pragma unroll 8
    for (int i = 0; i < 32; ++i) {
        int j = (i + j0) & 31;
        float4 x = pa[j], y = pb[j];
        s += x.x * y.x + x.y * y.y + x.z * y.z + x.w * y.w;
    }
    s += __shfl_xor(s, 1);
    s += __shfl_xor(s, 2);
    s += __shfl_xor(s, 4);
    if (slice == 0) sg[a][b] = s * sinv[a] * sinv[b];
    __syncthreads();
    if (t < 8) {
        float mn = 1e30f;
        int idx = 0;
        #pragma unroll
        for (int b2 = 0; b2 < 8; ++b2) {
            if (b2 == t) continue;
            float v = sg[t][b2];
            mn = fminf(mn, v);
            pos_sims[(size_t)(g * 8 + t) * 8 + idx] = v;
            ++idx;
        }
        min_pos[g * 8 + t] = mn;
    }
}

// ---------------- K2: fp8 MFMA sim tiles; 4 independent tile-waves per block ----------
// (best-known config, unchanged.) grid 520 x 256 threads = 2080 tile-waves; NO
// barriers. Per wave: private depth-3 LDS ring (12 KB); per k-step: counted vmcnt(8)
// -> 8 ds_read_b64 -> 16 MFMA -> lgkm(0) -> re-stage just-read buffer.
__global__ __launch_bounds__(256, 2) void k_neg(const unsigned long* __restrict__ xn8,
                                                const float* __restrict__ min_pos,
                                                float* __restrict__ sum_part,
                                                int* __restrict__ cnt_part,
                                                float* __restrict__ max_part,
                                                unsigned* __restrict__ gmax) {
    __shared__ char sbuf[4][3][4096];   // [wave][stage][A 2KB | B 2KB] = 48 KB

    int t = threadIdx.x;
    int w = t >> 6;          // wave id 0..3
    int l = t & 63;
    int u = blockIdx.x * 4 + w;   // tile unit 0..2079

    // decode triangular tile index (rt, ct), ct >= rt, over 64 bands
    int rt = 0, rem = u;
    while (rem >= NB - rt) { rem -= NB - rt; ++rt; }
    int ct = rt + rem;
    bool diag = (rt == ct);

    int R0 = rt * 64, C0 = ct * 64;
    int lrow = l & 15;
    int kgrp = l >> 4;

    float mA = min_pos[R0 + l];
    float mB = min_pos[C0 + l];
    asm volatile("s_waitcnt vmcnt(0)" ::: "memory");   // exact vmcnt bookkeeping below

    const char* xb = (const char*)xn8;
    const char* gA = xb + (size_t)rt * 65536 + (size_t)l * 16;
    const char* gB = xb + (size_t)ct * 65536 + (size_t)l * 16;
    char* ring = &sbuf[w][0][0];

    #define STAGE(s_)                                                   \
        do {                                                            \
            char* d_ = ring + ((s_) % 3) * 4096;                        \
            gld16(gA + (size_t)(s_) * 2048,        d_);                 \
            gld16(gA + (size_t)(s_) * 2048 + 1024, d_ + 1024);          \
            gld16(gB + (size_t)(s_) * 2048,        d_ + 2048);          \
            gld16(gB + (size_t)(s_) * 2048 + 1024, d_ + 3072);          \
        } while (0)

    STAGE(0); STAGE(1); STAGE(2);

    f32x4 zero = {0.f, 0.f, 0.f, 0.f};
    f32x4 acc[4][4];
    #pragma unroll
    for (int m = 0; m < 4; ++m)
        #pragma unroll
        for (int n = 0; n < 4; ++n) acc[m][n] = zero;

    for (int it = 0; it < 32; ++it) {
        // retire stage `it` (4 loads); keep up to 2 stages in flight
        if (it <= 29)      asm volatile("s_waitcnt vmcnt(8)" ::: "memory");
        else if (it == 30) asm volatile("s_waitcnt vmcnt(4)" ::: "memory");
        else               asm volatile("s_waitcnt vmcnt(0)" ::: "memory");

        const char* buf = ring + (it % 3) * 4096;
        long a[4], b[4];
        #pragma unroll
        for (int m = 0; m < 4; ++m) {
            a[m] = *(const long*)(buf + m * 512 + l * 8);
            b[m] = *(const long*)(buf + 2048 + m * 512 + l * 8);
        }

        // MFMAs overlap ds_read returns (compiler inserts partial lgkm waits)
        #pragma unroll
        for (int m = 0; m < 4; ++m)
            #pragma unroll
            for (int n = 0; n < 4; ++n)
                acc[m][n] = __builtin_amdgcn_mfma_f32_16x16x32_fp8_fp8(
                    a[m], b[n], acc[m][n], 0, 0, 0);

        // all reads of buf consumed -> safe to overwrite its ring slot
        asm volatile("s_waitcnt lgkmcnt(0)" ::: "memory");
        if (it <= 28) STAGE(it + 3);
    }
    #undef STAGE

    // ---- epilogue: row-band stats; col-band (transpose) stats for off-diag ----
    float allmax = -1e30f;

    float thB[4];
    #pragma unroll
    for (int n = 0; n < 4; ++n) thB[n] = __shfl(mB, n * 16 + lrow) - 0.05f;

    float colS[4] = {0.f, 0.f, 0.f, 0.f};
    float colM[4] = {-1e30f, -1e30f, -1e30f, -1e30f};
    int   colC[4] = {0, 0, 0, 0};

    #pragma unroll
    for (int m = 0; m < 4; ++m) {
        #pragma unroll
        for (int reg = 0; reg < 4; ++reg) {
            int lr = m * 16 + kgrp * 4 + reg;   // local row in [0,64)
            int grow = R0 + lr;
            float th = __shfl(mA, lr) - 0.05f;
            int gi = grow >> 3;
            float rs = 0.f, rm = -1e30f;
            int rc = 0;
            #pragma unroll
            for (int n = 0; n < 4; ++n) {
                int gcol = C0 + n * 16 + lrow;
                float s = acc[m][n][reg];
                allmax = fmaxf(allmax, s);
                if ((gcol >> 3) != gi) {
                    float e = softplus(ALPHA * (s - MARGIN));
                    rm = fmaxf(rm, s);
                    if (s > th) { rs += e; rc += 1; }
                    if (!diag) {
                        colM[n] = fmaxf(colM[n], s);
                        if (s > thB[n]) { colS[n] += e; colC[n] += 1; }
                    }
                }
            }
            #pragma unroll
            for (int off = 1; off < 16; off <<= 1) {
                rs += __shfl_xor(rs, off);
                rc += __shfl_xor(rc, off);
                rm = fmaxf(rm, __shfl_xor(rm, off));
            }
            if (lrow == 0) {
                sum_part[(size_t)grow * 64 + ct] = rs;
                cnt_part[(size_t)grow * 64 + ct] = rc;
                max_part[(size_t)grow * 64 + ct] = rm;
            }
        }
    }

    if (!diag) {
        #pragma unroll
        for (int n = 0; n < 4; ++n) {
            float cs = colS[n], cm = colM[n];
            int cc = colC[n];
            cs += __shfl_xor(cs, 16); cs += __shfl_xor(cs, 32);
            cc += __shfl_xor(cc, 16); cc += __shfl_xor(cc, 32);
            cm = fmaxf(cm, __shfl_xor(cm, 16));
            cm = fmaxf(cm, __shfl_xor(cm, 32));
            if (kgrp == 0) {
                int gcol = C0 + n * 16 + lrow;
                sum_part[(size_t)gcol * 64 + rt] = cs;
                cnt_part[(size_t)gcol * 64 + rt] = cc;
                max_part[(size_t)gcol * 64 + rt] = cm;
            }
        }
    }

    #pragma unroll
    for (int off = 1; off < 64; off <<= 1) allmax = fmaxf(allmax, __shfl_xor(allmax, off));
    if (l == 0) atomicMax(gmax, fkey(allmax));
}

// ---------------- K3: per-row combine (64 slots/row) + spread-atomic final mean ----------------
__global__ __launch_bounds__(256) void k_rowfinal(const float* __restrict__ sum_part,
                                                  const int* __restrict__ cnt_part,
                                                  const float* __restrict__ max_part,
                                                  const float* __restrict__ pos_sims,
                                                  const float* __restrict__ min_pos,
                                                  const unsigned* __restrict__ gmax,
                                                  float* __restrict__ accum,
                                                  unsigned* __restrict__ cnt,
                                                  float* __restrict__ out) {
    __shared__ float sloss[4];
    int row = blockIdx.x * 4 + (threadIdx.x >> 6);
    int lane = threadIdx.x & 63;
    float ns = sum_part[(size_t)row * 64 + lane];
    int nc = cnt_part[(size_t)row * 64 + lane];
    float nm = max_part[(size_t)row * 64 + lane];
    #pragma unroll
    for (int off = 1; off < 64; off <<= 1) {
        ns += __shfl_xor(ns, off);
        nc += __shfl_xor(nc, off);
        nm = fmaxf(nm, __shfl_xor(nm, off));
    }
    if (lane == 0) {
        float base = fmaxf(fdec(*gmax) - 0.1f, MARGIN + 0.2f);
        float neg_loss = (nc > 0) ? ns / (float)nc : softplus(ALPHA * (nm - MARGIN));
        float ps = 0.f;
        int pcnt = 0;
        float mn = min_pos[row];
        #pragma unroll
        for (int i = 0; i < NINST - 1; ++i) {
            float s = pos_sims[(size_t)row * 8 + i];
            if (s < base) { ps += softplus(-2.0f * (s - MARGIN)); pcnt++; }
        }
        float pos_loss = (pcnt > 0) ? ps / (float)pcnt : softplus(-2.0f * (mn - MARGIN));
        sloss[threadIdx.x >> 6] = pos_loss + neg_loss;
    }
    __syncthreads();
    if (threadIdx.x == 0) {
        float bs = sloss[0] + sloss[1] + sloss[2] + sloss[3];
        atomicAdd(&accum[blockIdx.x & 31], bs);
        __threadfence();
        unsigned old = atomicAdd(cnt, 1u);
        if (old == gridDim.x - 1) {
            __threadfence();
            float tot = 0.f;
            for (int j = 0; j < 32; ++j) tot += atomicAdd(&accum[j], 0.0f);
            out[0] = tot / (float)N;
        }
    }
}

extern "C" void kernel_launch(void* const* d_in, const int* in_sizes, int n_in,
                              void* d_out, int out_size, void* d_ws, size_t ws_size,
                              hipStream_t stream) {
    const float* in = (const float*)d_in[0];
    float* out = (float*)d_out;

    char* ws = (char*)d_ws;
    unsigned long* xn8 = (unsigned long*)(ws);                  // 4 MB (banded fragment-major)
    float*   min_pos  = (float*)(ws + 8388608 + 16384);         // 16 KB
    float*   pos_sims = (float*)(ws + 8388608 + 32768);         // 128 KB
    float*   sum_part = (float*)(ws + 8388608 + 32768 + 131072);            // 1 MB
    float*   max_part = (float*)(ws + 8388608 + 32768 + 131072 + 1048576);  // 1 MB
    int*     cnt_part = (int*)  (ws + 8388608 + 32768 + 131072 + 2097152);  // 1 MB
    unsigned* gmax    = (unsigned*)(ws + 8388608 + 32768 + 131072 + 3145728);
    float*   accum    = (float*)(ws + 8388608 + 32768 + 131072 + 3145728 + 128);  // 32 floats
    unsigned* cnt     = (unsigned*)(ws + 8388608 + 32768 + 131072 + 3145728 + 256);

    k_normpos<<<NGROUP, 512, 0, stream>>>(in, xn8, pos_sims, min_pos, gmax, accum, cnt);
    k_neg<<<NTILE / 4, 256, 0, stream>>>(xn8, min_pos, sum_part, cnt_part, max_part, gmax);
    k_rowfinal<<<N / 4, 256, 0, stream>>>(sum_part, cnt_part, max_part, pos_sims, min_pos,
                                          gmax, accum, cnt, out);
}